// Round 17
// baseline (40.313 us; speedup 1.0000x reference)
//
#include <hip/hip_runtime.h>
#include <hip/hip_bf16.h>

// Problem constants
#define HSZ 32
#define HP1 33
#define M3 35937            // 33^3 (flattened j,k,l)
#define M3P 35952           // padded to multiple of 16 (2247*16)
#define TI_STRIDE 1149984   // 33^3 * 32 floats (stride of T over i)
#define TIB ((size_t)TI_STRIDE * 4)
#define NBLK 2247           // one wave per block
#define NT 64               // partial output tiles (contention 2247/64 ~ 35)
#define DEPTH 8             // LDS ring slots (rows in flight)

// ws layout (bytes): a0T @ 0 ; D @ 8192 ; tiles @ 4610048
#define OFF_A0T   0
#define OFF_D     8192
#define OFF_TILES 4610048

typedef short bf16x8 __attribute__((ext_vector_type(8)));
typedef float f32x16 __attribute__((ext_vector_type(16)));

__device__ inline short f2bf(float f) {
  __hip_bfloat16 h = __float2bfloat16(f);  // RTNE; pairs into v_cvt_pk_bf16_f32
  return __builtin_bit_cast(short, h);
}

// Prologue, slimmed: 4 m's per thread, float4 D stores. Grid dim3(36,32).
__global__ __launch_bounds__(256) void k_pre(const float* __restrict__ nh,
                                             float* __restrict__ a0T,
                                             float* __restrict__ D,
                                             float* __restrict__ tiles) {
  const int b = blockIdx.y;
  const int m4 = (blockIdx.x * 256 + threadIdx.x) * 4;
  if (m4 < M3P) {
    const float* row = nh + b * 128;
    float4 v;
#pragma unroll
    for (int q = 0; q < 4; ++q) {
      const int m = m4 + q;
      float vv = 0.f;
      if (m < M3) {
        const int j = m / 1089;
        const int r = m - j * 1089;
        const int k = r / 33;
        const int l = r - k * 33;
        const float a1 = (j < HSZ) ? row[32 + j] : 1.0f;
        const float a2 = (k < HSZ) ? row[64 + k] : 1.0f;
        const float a3 = (l < HSZ) ? row[96 + l] : 1.0f;
        vv = a1 * a2 * a3;
      }
      (&v.x)[q] = vv;
    }
    *(float4*)(D + (size_t)b * M3P + m4) = v;
  }
  if (blockIdx.x == 0 && threadIdx.x < HP1) {
    const int i = threadIdx.x;
    a0T[i * 32 + b] = (i < HSZ) ? nh[(b * 4 + 0) * HSZ + i] : 1.0f;
  }
  if ((blockIdx.x == 1 || blockIdx.x == 2) && b < 32) {
    const int z = ((int)blockIdx.x - 1) * 32 + b;  // 0..63
    ((float4*)tiles)[z * 256 + threadIdx.x] = make_float4(0.f, 0.f, 0.f, 0.f);
  }
}

// Main (r16 verbatim): one wave per block; T-rows stream through an 8-slot
// LDS ring via global_load_lds, counted vmcnt(14) steady state.
__global__ __launch_bounds__(64) void k_main(const float* __restrict__ T,
                                             const float* __restrict__ a0T,
                                             const float* __restrict__ D,
                                             float* __restrict__ tiles) {
  __shared__ float lds[DEPTH * 512];  // 8 slots x 2048 B
  const int blk = blockIdx.x;
  const int m0 = blk * 16;
  const int l = (int)threadIdx.x;  // 0..63
  const int bo = l & 31;           // A row (b) / B col (o)
  const int g = l >> 5;            // k-group: k = 8*g + e

  // A-side D fragment: D[bo][m0+8g+e]
  const float* dp = D + (size_t)bo * M3P + m0 + 8 * g;
  float df[8];
  *(float4*)(df)     = *(const float4*)(dp);
  *(float4*)(df + 4) = *(const float4*)(dp + 4);

  // a0 preload into registers
  float a0v[HP1];
#pragma unroll
  for (int i = 0; i < HP1; ++i) a0v[i] = a0T[i * 32 + bo];

  // Drain df/a0 loads BEFORE the DMA stream so vmcnt accounting stays pure.
  {
    float dsum = 0.f, asum = 0.f;
#pragma unroll
    for (int e = 0; e < 8; ++e) dsum += df[e];
#pragma unroll
    for (int i = 0; i < HP1; ++i) asum += a0v[i];
    asm volatile("" :: "v"(dsum), "v"(asum) : "memory");
  }

  // Per-lane DMA source byte offsets (16B/lane, 2 halves per row).
  const int mrel = l >> 3;
  const size_t src0 = (m0 + mrel < M3) ? ((size_t)(m0 * 32 + l * 4) * 4) : 0;
  const size_t src1 =
      (m0 + 8 + mrel < M3) ? ((size_t)(m0 * 32 + 256 + l * 4) * 4) : 0;
  const char* Tb = (const char*)T;

#define ISSUE(row_, slot_)                                                   \
  {                                                                          \
    const char* s0p_ = Tb + (size_t)(row_)*TIB + src0;                       \
    const char* s1p_ = Tb + (size_t)(row_)*TIB + src1;                       \
    __builtin_amdgcn_global_load_lds(                                        \
        (const __attribute__((address_space(1))) void*)s0p_,                 \
        (__attribute__((address_space(3))) void*)(&lds[(slot_)*512]),        \
        16, 0, 0);                                                           \
    __builtin_amdgcn_global_load_lds(                                        \
        (const __attribute__((address_space(1))) void*)s1p_,                 \
        (__attribute__((address_space(3))) void*)(&lds[(slot_)*512 + 256]),  \
        16, 0, 0);                                                           \
  }

  // Prologue: fill the ring (16 DMA ops in flight)
  ISSUE(0, 0) ISSUE(1, 1) ISSUE(2, 2) ISSUE(3, 3)
  ISSUE(4, 4) ISSUE(5, 5) ISSUE(6, 6) ISSUE(7, 7)

  f32x16 acc = {};

#define STEP(i_, vm_, doIssue_)                                              \
  {                                                                          \
    asm volatile("s_waitcnt vmcnt(" #vm_ ")" ::: "memory");                  \
    __builtin_amdgcn_sched_barrier(0);                                       \
    float tvv[8];                                                            \
    _Pragma("unroll")                                                        \
    for (int e = 0; e < 8; ++e)                                              \
      tvv[e] = lds[((i_) % DEPTH) * 512 + (8 * g + e) * 32 + bo];            \
    asm volatile("s_waitcnt lgkmcnt(0)" ::: "memory");                       \
    if (doIssue_) ISSUE((i_) + DEPTH, (i_) % DEPTH)                          \
    bf16x8 af, bfr;                                                          \
    _Pragma("unroll")                                                        \
    for (int e = 0; e < 8; ++e) {                                            \
      af[e] = f2bf(a0v[i_] * df[e]);                                         \
      bfr[e] = f2bf(tvv[e]);                                                 \
    }                                                                        \
    acc = __builtin_amdgcn_mfma_f32_32x32x16_bf16(af, bfr, acc, 0, 0, 0);    \
  }

  // 33 explicit steps: steady vmcnt(14); descending drain from i=26.
  STEP(0, 14, 1)  STEP(1, 14, 1)  STEP(2, 14, 1)  STEP(3, 14, 1)
  STEP(4, 14, 1)  STEP(5, 14, 1)  STEP(6, 14, 1)  STEP(7, 14, 1)
  STEP(8, 14, 1)  STEP(9, 14, 1)  STEP(10, 14, 1) STEP(11, 14, 1)
  STEP(12, 14, 1) STEP(13, 14, 1) STEP(14, 14, 1) STEP(15, 14, 1)
  STEP(16, 14, 1) STEP(17, 14, 1) STEP(18, 14, 1) STEP(19, 14, 1)
  STEP(20, 14, 1) STEP(21, 14, 1) STEP(22, 14, 1) STEP(23, 14, 1)
  STEP(24, 14, 1) STEP(25, 14, 0) STEP(26, 12, 0) STEP(27, 10, 0)
  STEP(28, 8, 0)  STEP(29, 6, 0)  STEP(30, 4, 0)  STEP(31, 2, 0)
  STEP(32, 0, 0)
#undef STEP
#undef ISSUE

  // Accumulate into one of NT partial tiles (r12 epilogue verbatim).
  // C/D layout (m74/m101): col=lane&31, row=(r&3)+8*(r>>2)+4*(lane>>5)
  float* tp = tiles + (size_t)(blk & (NT - 1)) * 1024;
#pragma unroll
  for (int r = 0; r < 16; ++r) {
    const int brow = (r & 3) + 8 * (r >> 2) + 4 * g;
    atomicAdd(tp + brow * 32 + bo, acc[r]);
  }
}

// Final reduce (r12 verbatim): out[idx] = sum over NT tiles.
__global__ __launch_bounds__(256) void k_red(const float* __restrict__ tiles,
                                             float* __restrict__ out) {
  const int idx = blockIdx.x * 256 + (int)threadIdx.x;
  float s = 0.f;
  for (int t = 0; t < NT; ++t) s += tiles[(size_t)t * 1024 + idx];
  out[idx] = s;
}

extern "C" void kernel_launch(void* const* d_in, const int* in_sizes, int n_in,
                              void* d_out, int out_size, void* d_ws, size_t ws_size,
                              hipStream_t stream) {
  const float* nh = (const float*)d_in[0];  // [32,4,32]
  const float* T  = (const float*)d_in[1];  // [33,33,33,33,32]
  float* out = (float*)d_out;               // [32,32] fp32
  char* ws = (char*)d_ws;
  float* a0T   = (float*)(ws + OFF_A0T);
  float* D     = (float*)(ws + OFF_D);
  float* tiles = (float*)(ws + OFF_TILES);

  k_pre<<<dim3(36, 32), 256, 0, stream>>>(nh, a0T, D, tiles);
  k_main<<<NBLK, 64, 0, stream>>>(T, a0T, D, tiles);
  k_red<<<4, 256, 0, stream>>>(tiles, out);
}